// Round 14
// baseline (175.154 us; speedup 1.0000x reference)
//
#include <hip/hip_runtime.h>
#include <math.h>

#define BB 16
#define GG 512
#define PP 512
#define EE 256
#define HH 16
#define KD 16
#define HK 256

typedef __bf16 bf16x8 __attribute__((ext_vector_type(8)));
typedef __bf16 bf16x4 __attribute__((ext_vector_type(4)));
typedef float f32x4 __attribute__((ext_vector_type(4)));
typedef float f32x16 __attribute__((ext_vector_type(16)));
typedef int i32x4 __attribute__((ext_vector_type(4)));

// LDS geometry for fused_proj (bytes): compute phase 30720, epilogue 29184.
#define SA_STRIDE 40           // 32 cols + 8 pad (80B rows: 16B-aligned, <=4-way banks)
#define SMEM_BYTES 30720

__device__ inline void cvt_split8(const float* __restrict__ p, bf16x8& h, bf16x8& l)
{
    float4 f0 = *(const float4*)p;
    float4 f1 = *(const float4*)(p + 4);
    float v[8] = {f0.x, f0.y, f0.z, f0.w, f1.x, f1.y, f1.z, f1.w};
#pragma unroll
    for (int j = 0; j < 8; ++j) {
        __bf16 hh = (__bf16)v[j];
        h[j] = hh;
        l[j] = (__bf16)(v[j] - (float)hh);
    }
}

// v_cvt_pk_bf16_f32: packs 2 f32 -> u32 of 2 bf16 (RNE; lo=src0, hi=src1).
// No builtin on gfx950 (T12 recipe) -> inline asm.
__device__ inline int cvt_pk_bf16(float lo, float hi)
{
    int r;
    asm("v_cvt_pk_bf16_f32 %0, %1, %2" : "=v"(r) : "v"(lo), "v"(hi));
    return r;
}

// ---------------------------------------------------------------------------
// W2 precompute body: W2t[b][p][n] = sum_e enc[b,p,e] * Wc[n,e]  (hi/lo out),
// plus biasEnc[b][p] = sum_e Wcb[e]*enc[b,p,e] (exact fp32, n0==0 blocks).
// ---------------------------------------------------------------------------
__device__ inline void w2proj_body(int bx, int tid, unsigned char* smem,
                                   const float* __restrict__ enc,
                                   const float* __restrict__ Wc,
                                   const float* __restrict__ bias,
                                   __bf16* __restrict__ W2th,
                                   __bf16* __restrict__ W2tl,
                                   float* __restrict__ biasEnc)
{
    __bf16* sAh = (__bf16*)smem;               // enc tile  [64 p][32 e] hi
    __bf16* sAl = sAh + 64 * SA_STRIDE;        // lo
    __bf16* sBh = sAl + 64 * SA_STRIDE;        // Wc tile   [64 n][32 e] hi
    __bf16* sBl = sBh + 64 * SA_STRIDE;        // lo

    const int lane = tid & 63;
    const int w = __builtin_amdgcn_readfirstlane(tid >> 6);
    const int b  = bx >> 5;
    const int t  = bx & 31;
    const int p0 = (t >> 2) * 64;
    const int n0 = (t & 3) * 64;
    const bool do_bias = (n0 == 0);
    const int wm = (w >> 1) * 32, wn = (w & 1) * 32;
    const int ln = lane & 15, kq = (lane >> 4) * 8;
    const int ar = tid >> 2, ac = (tid & 3) * 8;

    f32x4 acc[2][2];
#pragma unroll
    for (int i = 0; i < 2; ++i)
#pragma unroll
        for (int j = 0; j < 2; ++j) acc[i][j] = (f32x4){0.f, 0.f, 0.f, 0.f};
    float bacc = 0.f;

    for (int k0 = 0; k0 < EE; k0 += 32) {
        {
            const float* ap = enc + ((size_t)(b * PP + p0 + ar)) * EE + k0 + ac;
            float4 f0 = *(const float4*)ap;
            float4 f1 = *(const float4*)(ap + 4);
            float v[8] = {f0.x, f0.y, f0.z, f0.w, f1.x, f1.y, f1.z, f1.w};
            bf16x8 h8, l8;
#pragma unroll
            for (int j = 0; j < 8; ++j) {
                __bf16 hh = (__bf16)v[j];
                h8[j] = hh;
                l8[j] = (__bf16)(v[j] - (float)hh);
            }
            if (do_bias) {
#pragma unroll
                for (int j = 0; j < 8; ++j) bacc += v[j] * bias[k0 + ac + j];
            }
            *(bf16x8*)&sAh[ar * SA_STRIDE + ac] = h8;
            *(bf16x8*)&sAl[ar * SA_STRIDE + ac] = l8;
        }
        {
            bf16x8 h8, l8;
            cvt_split8(Wc + (size_t)(n0 + ar) * EE + k0 + ac, h8, l8);
            *(bf16x8*)&sBh[ar * SA_STRIDE + ac] = h8;
            *(bf16x8*)&sBl[ar * SA_STRIDE + ac] = l8;
        }
        __syncthreads();

        bf16x8 ah[2], al[2];
#pragma unroll
        for (int mt = 0; mt < 2; ++mt) {
            ah[mt] = *(const bf16x8*)&sAh[(wm + mt * 16 + ln) * SA_STRIDE + kq];
            al[mt] = *(const bf16x8*)&sAl[(wm + mt * 16 + ln) * SA_STRIDE + kq];
        }
#pragma unroll
        for (int nt = 0; nt < 2; ++nt) {
            const int rowb = wn + nt * 16 + ln;
            bf16x8 bh8 = *(const bf16x8*)&sBh[rowb * SA_STRIDE + kq];
            bf16x8 bl8 = *(const bf16x8*)&sBl[rowb * SA_STRIDE + kq];
#pragma unroll
            for (int mt = 0; mt < 2; ++mt) {
                acc[mt][nt] = __builtin_amdgcn_mfma_f32_16x16x32_bf16(ah[mt], bh8, acc[mt][nt], 0, 0, 0);
                acc[mt][nt] = __builtin_amdgcn_mfma_f32_16x16x32_bf16(al[mt], bh8, acc[mt][nt], 0, 0, 0);
                acc[mt][nt] = __builtin_amdgcn_mfma_f32_16x16x32_bf16(ah[mt], bl8, acc[mt][nt], 0, 0, 0);
            }
        }
        __syncthreads();
    }

    if (do_bias) {
        bacc += __shfl_xor(bacc, 1);
        bacc += __shfl_xor(bacc, 2);
        if ((tid & 3) == 0) biasEnc[b * PP + p0 + ar] = bacc;
    }

    const int rbase = (lane >> 4) * 4;
#pragma unroll
    for (int mt = 0; mt < 2; ++mt)
#pragma unroll
        for (int nt = 0; nt < 2; ++nt)
#pragma unroll
            for (int r = 0; r < 4; ++r) {
                const int p = p0 + wm + mt * 16 + rbase + r;
                const int n = n0 + wn + nt * 16 + ln;
                const float v = acc[mt][nt][r];
                const __bf16 h = (__bf16)v;
                const size_t o = ((size_t)(b * PP + p)) * HK + n;
                W2th[o] = h;
                W2tl[o] = (__bf16)(v - (float)h);
            }
}

// ---------------------------------------------------------------------------
// weight_prep (round-9 arrangement): blocks [0,512) = W2 precompute;
// blocks [512,1344) = q1 partials + Wk/Wv/Wq transposes. Grid EXACTLY 1344.
// ---------------------------------------------------------------------------
__global__ __launch_bounds__(256) void weight_prep(const float* __restrict__ Wk,
                                                   const float* __restrict__ Wv,
                                                   const float* __restrict__ Wq,
                                                   const float* __restrict__ Wc,
                                                   const float* __restrict__ in1,
                                                   const float* __restrict__ enc,
                                                   const float* __restrict__ Wcb,
                                                   __bf16* __restrict__ wkt_h, __bf16* __restrict__ wkt_l,
                                                   __bf16* __restrict__ wvt_h, __bf16* __restrict__ wvt_l,
                                                   __bf16* __restrict__ wqt_h, __bf16* __restrict__ wqt_l,
                                                   float* __restrict__ q1p,
                                                   __bf16* __restrict__ W2th, __bf16* __restrict__ W2tl,
                                                   float* __restrict__ biasEnc)
{
    __shared__ __align__(16) unsigned char smem[4 * 64 * SA_STRIDE * 2];
    if (blockIdx.x < 512) {
        w2proj_body(blockIdx.x, threadIdx.x, smem, enc, Wc, Wcb, W2th, W2tl, biasEnc);
        return;
    }
    int gid = (blockIdx.x - 512) * 256 + threadIdx.x;
    if (gid < 16384) {
        const int b = gid >> 10, q = (gid >> 8) & 3, n = gid & 255;
        const float* ip = in1 + (size_t)b * EE + q * 64;
        const float* wp = Wq + (size_t)(q * 64) * HK + n;
        float acc = 0.f;
#pragma unroll 8
        for (int k = 0; k < 64; ++k) acc += ip[k] * wp[(size_t)k * HK];
        q1p[gid] = acc;
        return;
    }
    int id = gid - 16384;
    if (id >= 196608) return;   // guard: grid oversubscription must not write OOB
    const float* W;
    __bf16 *th, *tl;
    int krow = 0;
    if (id < 65536)       { W = Wk; th = wkt_h; tl = wkt_l; }
    else if (id < 131072) { id -= 65536;  W = Wv; th = wvt_h; tl = wvt_l; }
    else                  { id -= 131072; W = Wq; th = wqt_h; tl = wqt_l; krow = 256; }
    const int k = id & 255;
    const int n = id >> 8;
    const float v = W[(size_t)(k + krow) * HK + n];
    const __bf16 h = (__bf16)v;
    th[(n << 8) + k] = h;
    tl[(n << 8) + k] = (__bf16)(v - (float)h);
}

// ---------------------------------------------------------------------------
// LDS-staged fused K/V projection body (verified).
// ---------------------------------------------------------------------------
__device__ inline void kvproj_body(int bx, int tid, unsigned char* smem,
                                   const float* __restrict__ A,
                                   const __bf16* __restrict__ Bkh,
                                   const __bf16* __restrict__ Bkl,
                                   const __bf16* __restrict__ Bvh,
                                   const __bf16* __restrict__ Bvl,
                                   __bf16* __restrict__ Khi,
                                   __bf16* __restrict__ Klo,
                                   __bf16* __restrict__ Vt)
{
    __bf16* sAh = (__bf16*)smem;               // [64][SA_STRIDE]
    __bf16* sAl = sAh + 64 * SA_STRIDE;
    __bf16* sB  = sAl + 64 * SA_STRIDE;        // [4][64][SA_STRIDE]

    const int lane = tid & 63;
    const int w = __builtin_amdgcn_readfirstlane(tid >> 6);
    const int m0 = (bx >> 2) * 64;
    const int n0 = (bx & 3) * 64;
    const int wm = (w >> 1) * 32, wn = (w & 1) * 32;
    const int ln = lane & 15, kq = (lane >> 4) * 8;
    const int ar = tid >> 2, ac = (tid & 3) * 8;

    const __bf16* bsel = (w == 0) ? Bkh : (w == 1) ? Bkl : (w == 2) ? Bvh : Bvl;

    f32x4 ak[2][2], av[2][2];
#pragma unroll
    for (int i = 0; i < 2; ++i)
#pragma unroll
        for (int j = 0; j < 2; ++j) {
            ak[i][j] = (f32x4){0.f, 0.f, 0.f, 0.f};
            av[i][j] = (f32x4){0.f, 0.f, 0.f, 0.f};
        }

    for (int k0 = 0; k0 < EE; k0 += 32) {
        {
            bf16x8 h8, l8;
            cvt_split8(A + (size_t)(m0 + ar) * EE + k0 + ac, h8, l8);
            *(bf16x8*)&sAh[ar * SA_STRIDE + ac] = h8;
            *(bf16x8*)&sAl[ar * SA_STRIDE + ac] = l8;
        }
        {
            const __bf16* src = bsel + (size_t)(n0 + lane) * EE + k0;
            __bf16* dst = sB + (w * 64 + lane) * SA_STRIDE;
            *(bf16x8*)&dst[0]  = *(const bf16x8*)&src[0];
            *(bf16x8*)&dst[8]  = *(const bf16x8*)&src[8];
            *(bf16x8*)&dst[16] = *(const bf16x8*)&src[16];
            *(bf16x8*)&dst[24] = *(const bf16x8*)&src[24];
        }
        __syncthreads();

        bf16x8 ah[2], al[2];
#pragma unroll
        for (int mt = 0; mt < 2; ++mt) {
            ah[mt] = *(const bf16x8*)&sAh[(wm + mt * 16 + ln) * SA_STRIDE + kq];
            al[mt] = *(const bf16x8*)&sAl[(wm + mt * 16 + ln) * SA_STRIDE + kq];
        }
#pragma unroll
        for (int nt = 0; nt < 2; ++nt) {
            const int rowb = wn + nt * 16 + ln;
            bf16x8 bkh8 = *(const bf16x8*)&sB[(0 * 64 + rowb) * SA_STRIDE + kq];
            bf16x8 bkl8 = *(const bf16x8*)&sB[(1 * 64 + rowb) * SA_STRIDE + kq];
            bf16x8 bvh8 = *(const bf16x8*)&sB[(2 * 64 + rowb) * SA_STRIDE + kq];
            bf16x8 bvl8 = *(const bf16x8*)&sB[(3 * 64 + rowb) * SA_STRIDE + kq];
#pragma unroll
            for (int mt = 0; mt < 2; ++mt) {
                ak[mt][nt] = __builtin_amdgcn_mfma_f32_16x16x32_bf16(ah[mt], bkh8, ak[mt][nt], 0, 0, 0);
                ak[mt][nt] = __builtin_amdgcn_mfma_f32_16x16x32_bf16(al[mt], bkh8, ak[mt][nt], 0, 0, 0);
                ak[mt][nt] = __builtin_amdgcn_mfma_f32_16x16x32_bf16(ah[mt], bkl8, ak[mt][nt], 0, 0, 0);
                av[mt][nt] = __builtin_amdgcn_mfma_f32_16x16x32_bf16(ah[mt], bvh8, av[mt][nt], 0, 0, 0);
                av[mt][nt] = __builtin_amdgcn_mfma_f32_16x16x32_bf16(al[mt], bvh8, av[mt][nt], 0, 0, 0);
                av[mt][nt] = __builtin_amdgcn_mfma_f32_16x16x32_bf16(ah[mt], bvl8, av[mt][nt], 0, 0, 0);
            }
        }
        __syncthreads();
    }

    __bf16* eKh = (__bf16*)smem;
    __bf16* eKl = eKh + 5120;
    __bf16* eV  = eKl + 5120;

    const int rbase = (lane >> 4) * 4;
#pragma unroll
    for (int mt = 0; mt < 2; ++mt)
#pragma unroll
        for (int nt = 0; nt < 2; ++nt) {
            const int hloc = (w & 1) * 2 + nt;
            const int nl = wn + nt * 16 + ln;
#pragma unroll
            for (int r = 0; r < 4; ++r) {
                const int m = wm + mt * 16 + rbase + r;
                const float vk = ak[mt][nt][r];
                const __bf16 hk = (__bf16)vk;
                eKh[(hloc * 64 + m) * 20 + ln] = hk;
                eKl[(hloc * 64 + m) * 20 + ln] = (__bf16)(vk - (float)hk);
                eV[nl * 68 + m] = (__bf16)av[mt][nt][r];
            }
        }
    __syncthreads();

    const int b = m0 >> 9;
    const int pbase = m0 & (PP - 1);
    {
        const int hl = tid >> 6, p = tid & 63;
        const int hg = (n0 >> 4) + hl;
        const size_t dst = (((size_t)b * HH + hg) * PP + pbase + p) * KD;
        const int base = (hl * 64 + p) * 20;
        uint2 a0 = *(const uint2*)&eKh[base + 0];
        uint2 a1 = *(const uint2*)&eKh[base + 4];
        uint2 a2 = *(const uint2*)&eKh[base + 8];
        uint2 a3 = *(const uint2*)&eKh[base + 12];
        *(uint4*)(Khi + dst)     = make_uint4(a0.x, a0.y, a1.x, a1.y);
        *(uint4*)(Khi + dst + 8) = make_uint4(a2.x, a2.y, a3.x, a3.y);
        uint2 c0 = *(const uint2*)&eKl[base + 0];
        uint2 c1 = *(const uint2*)&eKl[base + 4];
        uint2 c2 = *(const uint2*)&eKl[base + 8];
        uint2 c3 = *(const uint2*)&eKl[base + 12];
        *(uint4*)(Klo + dst)     = make_uint4(c0.x, c0.y, c1.x, c1.y);
        *(uint4*)(Klo + dst + 8) = make_uint4(c2.x, c2.y, c3.x, c3.y);
    }
    {
        const int n = tid >> 2, qq = tid & 3;
        const int ng = n0 + n, hg = ng >> 4, kk = ng & 15;
        const int base = n * 68 + qq * 16;
        uint2 v0 = *(const uint2*)&eV[base + 0];
        uint2 v1 = *(const uint2*)&eV[base + 4];
        uint2 v2 = *(const uint2*)&eV[base + 8];
        uint2 v3 = *(const uint2*)&eV[base + 12];
        const size_t dst = ((((size_t)b * HH + hg) * KD + kk) * PP) + pbase + qq * 16;
        *(uint4*)(Vt + dst)     = make_uint4(v0.x, v0.y, v1.x, v1.y);
        *(uint4*)(Vt + dst + 8) = make_uint4(v2.x, v2.y, v3.x, v3.y);
    }
}

// ---------------------------------------------------------------------------
// LDS-staged Q projection body (verified).
// ---------------------------------------------------------------------------
__device__ inline void qproj_body(int bx, int tid, unsigned char* smem,
                                  const float* __restrict__ in2,
                                  const float* __restrict__ ct,
                                  const __bf16* __restrict__ Bh,
                                  const __bf16* __restrict__ Bl,
                                  const float* __restrict__ WqFull,
                                  const float* __restrict__ q1p,
                                  __bf16* __restrict__ Qhi,
                                  __bf16* __restrict__ Qlo)
{
    __bf16* sAh = (__bf16*)smem;
    __bf16* sAl = sAh + 64 * SA_STRIDE;
    __bf16* sB  = sAl + 64 * SA_STRIDE;

    const int lane = tid & 63;
    const int w = __builtin_amdgcn_readfirstlane(tid >> 6);
    const int m0 = (bx >> 2) * 64;
    const int n0 = (bx & 3) * 64;
    const int wm = (w >> 1) * 32, wn = (w & 1) * 32;
    const int ln = lane & 15, kq = (lane >> 4) * 8;
    const int ar = tid >> 2, ac = (tid & 3) * 8;
    const int b = m0 >> 9;
    const float* WqLast = WqFull + (size_t)512 * HK;

    f32x4 acc[2][2];
#pragma unroll
    for (int i = 0; i < 2; ++i)
#pragma unroll
        for (int j = 0; j < 2; ++j) acc[i][j] = (f32x4){0.f, 0.f, 0.f, 0.f};

    for (int k0 = 0; k0 < EE; k0 += 32) {
        {
            bf16x8 h8, l8;
            cvt_split8(in2 + (size_t)(m0 + ar) * EE + k0 + ac, h8, l8);
            *(bf16x8*)&sAh[ar * SA_STRIDE + ac] = h8;
            *(bf16x8*)&sAl[ar * SA_STRIDE + ac] = l8;
        }
        {
            const int mat = w >> 1;
            const int row = (w & 1) * 32 + (lane >> 1);
            const int half = (lane & 1) * 16;
            const __bf16* src = (mat ? Bl : Bh) + ((size_t)(n0 + row) << 8) + k0 + half;
            __bf16* dst = sB + (mat * 64 + row) * SA_STRIDE + half;
            *(bf16x8*)&dst[0] = *(const bf16x8*)&src[0];
            *(bf16x8*)&dst[8] = *(const bf16x8*)&src[8];
        }
        __syncthreads();

        bf16x8 ah[2], al[2];
#pragma unroll
        for (int mt = 0; mt < 2; ++mt) {
            ah[mt] = *(const bf16x8*)&sAh[(wm + mt * 16 + ln) * SA_STRIDE + kq];
            al[mt] = *(const bf16x8*)&sAl[(wm + mt * 16 + ln) * SA_STRIDE + kq];
        }
#pragma unroll
        for (int nt = 0; nt < 2; ++nt) {
            const int rowb = wn + nt * 16 + ln;
            bf16x8 bh8 = *(const bf16x8*)&sB[(0 * 64 + rowb) * SA_STRIDE + kq];
            bf16x8 bl8 = *(const bf16x8*)&sB[(1 * 64 + rowb) * SA_STRIDE + kq];
#pragma unroll
            for (int mt = 0; mt < 2; ++mt) {
                acc[mt][nt] = __builtin_amdgcn_mfma_f32_16x16x32_bf16(ah[mt], bh8, acc[mt][nt], 0, 0, 0);
                acc[mt][nt] = __builtin_amdgcn_mfma_f32_16x16x32_bf16(al[mt], bh8, acc[mt][nt], 0, 0, 0);
                acc[mt][nt] = __builtin_amdgcn_mfma_f32_16x16x32_bf16(ah[mt], bl8, acc[mt][nt], 0, 0, 0);
            }
        }
        __syncthreads();
    }

    __bf16* eQh = (__bf16*)smem;
    __bf16* eQl = eQh + 5120;

    const int rbase = (lane >> 4) * 4;
#pragma unroll
    for (int mt = 0; mt < 2; ++mt)
#pragma unroll
        for (int nt = 0; nt < 2; ++nt) {
            const int hloc = (w & 1) * 2 + nt;
            const int ng = n0 + wn + nt * 16 + ln;
            const float wq = WqLast[ng];
            const float q1v = q1p[b * 1024 + 0 * 256 + ng] + q1p[b * 1024 + 1 * 256 + ng]
                            + q1p[b * 1024 + 2 * 256 + ng] + q1p[b * 1024 + 3 * 256 + ng];
#pragma unroll
            for (int r = 0; r < 4; ++r) {
                const int m = wm + mt * 16 + rbase + r;
                const float v = acc[mt][nt][r] + q1v + ct[m0 + m] * wq;
                const __bf16 h = (__bf16)v;
                eQh[(hloc * 64 + m) * 20 + ln] = h;
                eQl[(hloc * 64 + m) * 20 + ln] = (__bf16)(v - (float)h);
            }
        }
    __syncthreads();

    {
        const int hl = tid >> 6, p = tid & 63;
        const int hg = (n0 >> 4) + hl;
        const int g = (m0 & (GG - 1)) + p;
        const size_t dst = (((size_t)b * HH + hg) * GG + g) * KD;
        const int base = (hl * 64 + p) * 20;
        uint2 a0 = *(const uint2*)&eQh[base + 0];
        uint2 a1 = *(const uint2*)&eQh[base + 4];
        uint2 a2 = *(const uint2*)&eQh[base + 8];
        uint2 a3 = *(const uint2*)&eQh[base + 12];
        *(uint4*)(Qhi + dst)     = make_uint4(a0.x, a0.y, a1.x, a1.y);
        *(uint4*)(Qhi + dst + 8) = make_uint4(a2.x, a2.y, a3.x, a3.y);
        uint2 c0 = *(const uint2*)&eQl[base + 0];
        uint2 c1 = *(const uint2*)&eQl[base + 4];
        uint2 c2 = *(const uint2*)&eQl[base + 8];
        uint2 c3 = *(const uint2*)&eQl[base + 12];
        *(uint4*)(Qlo + dst)     = make_uint4(c0.x, c0.y, c1.x, c1.y);
        *(uint4*)(Qlo + dst + 8) = make_uint4(c2.x, c2.y, c3.x, c3.y);
    }
}

// ---------------------------------------------------------------------------
// Fused K/V + Q projections: 1024 blocks.
// (256,2): do NOT raise to 3 — the VGPR cap forces K-loop spills (round 1).
// ---------------------------------------------------------------------------
__global__ __launch_bounds__(256, 2) void fused_proj(const float* __restrict__ enc,
                                                     const __bf16* __restrict__ Bkh,
                                                     const __bf16* __restrict__ Bkl,
                                                     const __bf16* __restrict__ Bvh,
                                                     const __bf16* __restrict__ Bvl,
                                                     __bf16* __restrict__ Khi,
                                                     __bf16* __restrict__ Klo,
                                                     __bf16* __restrict__ Vt,
                                                     const float* __restrict__ in2,
                                                     const float* __restrict__ ct,
                                                     const __bf16* __restrict__ Bqh,
                                                     const __bf16* __restrict__ Bql,
                                                     const float* __restrict__ WqFull,
                                                     const float* __restrict__ q1p,
                                                     __bf16* __restrict__ Qhi,
                                                     __bf16* __restrict__ Qlo)
{
    __shared__ __align__(16) unsigned char smem[SMEM_BYTES];
    const int id = blockIdx.x;
    if (id < 512)
        kvproj_body(id, threadIdx.x, smem, enc, Bkh, Bkl, Bvh, Bvl, Khi, Klo, Vt);
    else
        qproj_body(id - 512, threadIdx.x, smem, in2, ct, Bqh, Bql, WqFull, q1p, Qhi, Qlo);
}

// ---------------------------------------------------------------------------
// Fused attention + pointer head (round 13 = round-12 swapped-QK body with
// `#pragma unroll 4` on the attn loop). Rationale: r12 counters show ~50%
// stall with VGPR=52 (76 regs of headroom under the (1024,4) cap). unroll 4
// lets the scheduler hoist 2-3 iterations of the 6 independent 16B loads —
// unlike round 8's disaster this is compiler-scheduled (no manual dbuf) and
// has real register headroom. Tripwire: WRITE_SIZE must stay ~16 MB.
// ---------------------------------------------------------------------------
#define AT_STRIDE 264    // 256 + 8 pad
#define MSK_STRIDE 516   // 512 + 4 pad (f32): float4-aligned, <=4-way banks

__global__ __launch_bounds__(1024, 4) void attn_ptr(const __bf16* __restrict__ Qhi,
                                                    const __bf16* __restrict__ Qlo,
                                                    const __bf16* __restrict__ Khi,
                                                    const __bf16* __restrict__ Klo,
                                                    const __bf16* __restrict__ Vt,
                                                    const __bf16* __restrict__ w2_hi,
                                                    const __bf16* __restrict__ w2_lo,
                                                    const float* __restrict__ biasEnc,
                                                    const float* __restrict__ mask,
                                                    float* __restrict__ out)
{
    __shared__ __align__(16) float smask[32][MSK_STRIDE]; // 66 KB, mask slice
    __shared__ float srs[16][32];                         // row-sums / swsum
    __shared__ __align__(16) __bf16 sAth[32][AT_STRIDE];  // 16.9 KB, At hi
    __shared__ __align__(16) __bf16 sAtl[32][AT_STRIDE];  // 16.9 KB, At lo

    const int t = threadIdx.x;
    const int lane = t & 63;
    const int w = __builtin_amdgcn_readfirstlane(t >> 6);  // 0..15
    const int id = blockIdx.x;
    const int b = id & 15;                 // XCD pin: id%8 == b%8
    const int g0 = (id >> 4) * 32;
    const int ln32 = lane & 31;
    const int half = lane >> 5;
    const int h = w;                       // wave = head

    // ---- cooperative mask staging: 16384 f32 = 4 float4 per thread --------
    {
        const float* msrc = mask + ((size_t)(b * GG + g0)) * PP;
#pragma unroll
        for (int i = 0; i < 4; ++i) {
            const int c = (t + i * 1024) * 4;
            const int row = c >> 9, col = c & 511;
            *(float4*)&smask[row][col] = *(const float4*)&msrc[row * 512 + col];
        }
    }
    __syncthreads();   // mask staging visible to all waves

    // ================= attn phase (swapped QK) ==============================
    const size_t qbase = (((size_t)b * HH + h) * GG + g0) * KD;
    const size_t kbase = ((size_t)b * HH + h) * PP * KD;
    const size_t vbase = ((size_t)b * HH + h) * KD * PP;

    bf16x8 qah = *(const bf16x8*)(Qhi + qbase + (size_t)ln32 * KD + half * 8);
    bf16x8 qal = *(const bf16x8*)(Qlo + qbase + (size_t)ln32 * KD + half * 8);

    float rs = 0.f;
    f32x16 acc = (f32x16){0.f, 0.f, 0.f, 0.f, 0.f, 0.f, 0.f, 0.f,
                          0.f, 0.f, 0.f, 0.f, 0.f, 0.f, 0.f, 0.f};
    const int dv = ln32 & 15;   // V row (d), duplicated for ln32>=16

#pragma unroll 4
    for (int pc = 0; pc < 16; ++pc) {
        const int pb = pc * 32;
        const size_t ko = kbase + (size_t)(pb + ln32) * KD + half * 8;
        bf16x8 kh = *(const bf16x8*)(Khi + ko);
        bf16x8 kl = *(const bf16x8*)(Klo + ko);
        bf16x8 vb0 = *(const bf16x8*)(Vt + vbase + (size_t)dv * PP + pb + half * 8);
        bf16x8 vb1 = *(const bf16x8*)(Vt + vbase + (size_t)dv * PP + pb + 16 + half * 8);

        f32x16 s = (f32x16){0.f, 0.f, 0.f, 0.f, 0.f, 0.f, 0.f, 0.f,
                            0.f, 0.f, 0.f, 0.f, 0.f, 0.f, 0.f, 0.f};
        __builtin_amdgcn_s_setprio(1);
        s = __builtin_amdgcn_mfma_f32_32x32x16_bf16(kh, qah, s, 0, 0, 0);   // S^T
        s = __builtin_amdgcn_mfma_f32_32x32x16_bf16(kh, qal, s, 0, 0, 0);
        s = __builtin_amdgcn_mfma_f32_32x32x16_bf16(kl, qah, s, 0, 0, 0);
        __builtin_amdgcn_s_setprio(0);

        // mask: g = ln32 row, p = pb + prow(r,half); 4 float4 reads
        const float4 m0 = *(const float4*)&smask[ln32][pb + 0  + 4 * half];
        const float4 m1 = *(const float4*)&smask[ln32][pb + 8  + 4 * half];
        const float4 m2 = *(const float4*)&smask[ln32][pb + 16 + 4 * half];
        const float4 m3 = *(const float4*)&smask[ln32][pb + 24 + 4 * half];
        s[0]  = __expf(s[0]  * 0.25f + m0.x);
        s[1]  = __expf(s[1]  * 0.25f + m0.y);
        s[2]  = __expf(s[2]  * 0.25f + m0.z);
        s[3]  = __expf(s[3]  * 0.25f + m0.w);
        s[4]  = __expf(s[4]  * 0.25f + m1.x);
        s[5]  = __expf(s[5]  * 0.25f + m1.y);
        s[6]  = __expf(s[6]  * 0.25f + m1.z);
        s[7]  = __expf(s[7]  * 0.25f + m1.w);
        s[8]  = __expf(s[8]  * 0.25f + m2.x);
        s[9]  = __expf(s[9]  * 0.25f + m2.y);
        s[10] = __expf(s[10] * 0.25f + m2.z);
        s[11] = __expf(s[11] * 0.25f + m2.w);
        s[12] = __expf(s[12] * 0.25f + m3.x);
        s[13] = __expf(s[13] * 0.25f + m3.y);
        s[14] = __expf(s[14] * 0.25f + m3.z);
        s[15] = __expf(s[15] * 0.25f + m3.w);
#pragma unroll
        for (int r = 0; r < 16; ++r) rs += s[r];

        // pack P (bf16) and redistribute halves
        const int w01 = cvt_pk_bf16(s[0],  s[1]);
        const int w23 = cvt_pk_bf16(s[2],  s[3]);
        const int w45 = cvt_pk_bf16(s[4],  s[5]);
        const int w67 = cvt_pk_bf16(s[6],  s[7]);
        const int w89 = cvt_pk_bf16(s[8],  s[9]);
        const int wAB = cvt_pk_bf16(s[10], s[11]);
        const int wCD = cvt_pk_bf16(s[12], s[13]);
        const int wEF = cvt_pk_bf16(s[14], s[15]);
        const int x1 = half ? w01 : w45;
        const int x2 = half ? w23 : w67;
        const int x3 = half ? w89 : wCD;
        const int x4 = half ? wAB : wEF;
        const int p1 = __shfl_xor(x1, 32);
        const int p2 = __shfl_xor(x2, 32);
        const int p3 = __shfl_xor(x3, 32);
        const int p4 = __shfl_xor(x4, 32);
        i32x4 f0 = half ? (i32x4){p1, p2, w45, w67} : (i32x4){w01, w23, p1, p2};
        i32x4 f1 = half ? (i32x4){p3, p4, wCD, wEF} : (i32x4){w89, wAB, p3, p4};
        bf16x8 pa0 = *(bf16x8*)&f0;
        bf16x8 pa1 = *(bf16x8*)&f1;

        __builtin_amdgcn_s_setprio(1);
        acc = __builtin_amdgcn_mfma_f32_32x32x16_bf16(pa0, vb0, acc, 0, 0, 0);
        acc = __builtin_amdgcn_mfma_f32_32x32x16_bf16(pa1, vb1, acc, 0, 0, 0);
        __builtin_amdgcn_s_setprio(0);
    }

    // total row-sum for g = ln32: own half + partner half
    rs += __shfl_xor(rs, 32);
    if (half == 0) srs[w][ln32] = rs;

    // O layout: col = d = ln32 (valid < 16), reg r -> g = prow(r,half).
    if (ln32 < 16) {
#pragma unroll
        for (int r = 0; r < 16; ++r) {
            const int g = (r & 3) + 8 * (r >> 2) + 4 * half;
            const float v = acc[r] / srs[w][g];
            const __bf16 hv = (__bf16)v;
            sAth[g][w * 16 + ln32] = hv;
            sAtl[g][w * 16 + ln32] = (__bf16)(v - (float)hv);
        }
    }
    __syncthreads();

    // ================= pointer phase (A from LDS) ===========================
    const size_t brow = ((size_t)(b * PP + w * 32 + ln32)) * HK + half * 8;
    const float be = biasEnc[b * PP + w * 32 + ln32];

    f32x16 acc0 = (f32x16){0.f, 0.f, 0.f, 0.f, 0.f, 0.f, 0.f, 0.f,
                           0.f, 0.f, 0.f, 0.f, 0.f, 0.f, 0.f, 0.f};
    f32x16 acc1 = acc0, acc2 = acc0;

#pragma unroll 4
    for (int kc = 0; kc < HK; kc += 16) {
        bf16x8 ah = *(const bf16x8*)&sAth[ln32][kc + half * 8];
        bf16x8 al = *(const bf16x8*)&sAtl[ln32][kc + half * 8];
        bf16x8 bh = *(const bf16x8*)(w2_hi + brow + kc);
        bf16x8 bl = *(const bf16x8*)(w2_lo + brow + kc);
        __builtin_amdgcn_s_setprio(1);
        acc0 = __builtin_amdgcn_mfma_f32_32x32x16_bf16(ah, bh, acc0, 0, 0, 0);
        acc1 = __builtin_amdgcn_mfma_f32_32x32x16_bf16(al, bh, acc1, 0, 0, 0);
        acc2 = __builtin_amdgcn_mfma_f32_32x32x16_bf16(ah, bl, acc2, 0, 0, 0);
        __builtin_amdgcn_s_setprio(0);
    }

    f32x16 pacc = acc0 + acc1 + acc2;

    float rsum[16];
#pragma unroll
    for (int r = 0; r < 16; ++r) {
        const int row = (r & 3) + 8 * (r >> 2) + 4 * half;
        float sc = (pacc[r] + be) * 0.0625f;             // 1/sqrt(256)
        sc = fminf(9.f, fmaxf(-9.f, sc));
        const float e2 = __expf(2.f * sc);
        const float th = (e2 - 1.f) / (e2 + 1.f);        // tanh(sc)
        const float m = smask[row][w * 32 + ln32];
        const float e = __expf(10.f * th + m);           // bounded by e^10
        pacc[r] = e;
        rsum[r] = e;
    }

#pragma unroll
    for (int r = 0; r < 16; ++r) {
        rsum[r] += __shfl_xor(rsum[r], 1);
        rsum[r] += __shfl_xor(rsum[r], 2);
        rsum[r] += __shfl_xor(rsum[r], 4);
        rsum[r] += __shfl_xor(rsum[r], 8);
        rsum[r] += __shfl_xor(rsum[r], 16);
    }
    if (ln32 == 0) {
#pragma unroll
        for (int r = 0; r < 16; ++r)
            srs[w][(r & 3) + 8 * (r >> 2) + 4 * half] = rsum[r];   // reuse as swsum
    }
    __syncthreads();

    float inv[16];
#pragma unroll
    for (int r = 0; r < 16; ++r) {
        const int row = (r & 3) + 8 * (r >> 2) + 4 * half;
        float tot = 0.f;
#pragma unroll
        for (int wv = 0; wv < 16; ++wv) tot += srs[wv][row];  // LDS broadcast
        inv[r] = 1.f / tot;
    }

#pragma unroll
    for (int r = 0; r < 16; ++r) {
        const int row = (r & 3) + 8 * (r >> 2) + 4 * half;
        out[((size_t)(b * GG + g0 + row)) * PP + w * 32 + ln32] = pacc[r] * inv[r];
    }
}

// ---------------------------------------------------------------------------
extern "C" void kernel_launch(void* const* d_in, const int* in_sizes, int n_in,
                              void* d_out, int out_size, void* d_ws, size_t ws_size,
                              hipStream_t stream)
{
    const float* in1  = (const float*)d_in[0];
    const float* in2  = (const float*)d_in[1];
    const float* ct   = (const float*)d_in[2];
    const float* mask = (const float*)d_in[3];
    const float* enc  = (const float*)d_in[4];
    const float* Wq   = (const float*)d_in[5];
    const float* Wk   = (const float*)d_in[6];
    const float* Wv   = (const float*)d_in[7];
    const float* Wcw  = (const float*)d_in[8];
    const float* Wcb  = (const float*)d_in[9];
    float* out = (float*)d_out;
    float* ws  = (float*)d_ws;

    const size_t SEG = (size_t)BB * GG * HK;  // 2M elements
    __bf16* Khi = (__bf16*)ws;
    __bf16* Klo = Khi + SEG;
    __bf16* Vt  = (__bf16*)(ws + SEG);
    __bf16* Qhi = (__bf16*)(ws + 2 * SEG);
    __bf16* Qlo = Qhi + SEG;
    __bf16* wkt_h = (__bf16*)(ws + 3 * SEG);   // 6 x 65536 bf16 = 196608 floats
    __bf16* wkt_l = wkt_h + 65536;
    __bf16* wvt_h = wkt_l + 65536;
    __bf16* wvt_l = wvt_h + 65536;
    __bf16* wqt_h = wvt_l + 65536;             // Wq rows 256..511 only
    __bf16* wqt_l = wqt_h + 65536;
    float*  q1p     = ws + 3 * SEG + 196608;   // [B][4][HK] fp32 partials
    float*  biasEnc = q1p + 16384;             // [B][P] fp32
    __bf16* W2th  = (__bf16*)(ws + 4 * SEG);   // [B][P][HK] hi
    __bf16* W2tl  = W2th + SEG;                // lo

    const dim3 blk(256);

    weight_prep<<<dim3(1344), blk, 0, stream>>>(Wk, Wv, Wq, Wcw, in1, enc, Wcb,
                                                wkt_h, wkt_l, wvt_h, wvt_l,
                                                wqt_h, wqt_l, q1p,
                                                W2th, W2tl, biasEnc);

    fused_proj<<<dim3(1024), blk, 0, stream>>>(enc, wkt_h, wkt_l, wvt_h, wvt_l,
                                               Khi, Klo, Vt,
                                               in2, ct, wqt_h, wqt_l, Wq, q1p,
                                               Qhi, Qlo);

    attn_ptr<<<dim3(256), dim3(1024), 0, stream>>>(Qhi, Qlo, Khi, Klo, Vt,
                                                   W2th, W2tl, biasEnc, mask, out);
}

// Round 15
// 172.458 us; speedup vs baseline: 1.0156x; 1.0156x over previous
//
#include <hip/hip_runtime.h>
#include <math.h>

#define BB 16
#define GG 512
#define PP 512
#define EE 256
#define HH 16
#define KD 16
#define HK 256

typedef __bf16 bf16x8 __attribute__((ext_vector_type(8)));
typedef __bf16 bf16x4 __attribute__((ext_vector_type(4)));
typedef float f32x4 __attribute__((ext_vector_type(4)));
typedef float f32x16 __attribute__((ext_vector_type(16)));
typedef int i32x4 __attribute__((ext_vector_type(4)));

// LDS geometry (bytes): split-proj compute 20480, epilogues <= 20480.
#define SA_STRIDE 40           // 32 cols + 8 pad (80B rows: 16B-aligned, <=4-way banks)
#define SMEM_BYTES 20480

__device__ inline void cvt_split8(const float* __restrict__ p, bf16x8& h, bf16x8& l)
{
    float4 f0 = *(const float4*)p;
    float4 f1 = *(const float4*)(p + 4);
    float v[8] = {f0.x, f0.y, f0.z, f0.w, f1.x, f1.y, f1.z, f1.w};
#pragma unroll
    for (int j = 0; j < 8; ++j) {
        __bf16 hh = (__bf16)v[j];
        h[j] = hh;
        l[j] = (__bf16)(v[j] - (float)hh);
    }
}

// v_cvt_pk_bf16_f32: packs 2 f32 -> u32 of 2 bf16 (RNE; lo=src0, hi=src1).
__device__ inline int cvt_pk_bf16(float lo, float hi)
{
    int r;
    asm("v_cvt_pk_bf16_f32 %0, %1, %2" : "=v"(r) : "v"(lo), "v"(hi));
    return r;
}

// ---------------------------------------------------------------------------
// W2 precompute body: W2t[b][p][n] = sum_e enc[b,p,e] * Wc[n,e]  (hi/lo out),
// plus biasEnc[b][p] = sum_e Wcb[e]*enc[b,p,e] (exact fp32, n0==0 blocks).
// Own LDS (30.7 KB) — lives in weight_prep only.
// ---------------------------------------------------------------------------
__device__ inline void w2proj_body(int bx, int tid, unsigned char* smem,
                                   const float* __restrict__ enc,
                                   const float* __restrict__ Wc,
                                   const float* __restrict__ bias,
                                   __bf16* __restrict__ W2th,
                                   __bf16* __restrict__ W2tl,
                                   float* __restrict__ biasEnc)
{
    __bf16* sAh = (__bf16*)smem;               // enc tile  [64 p][32 e] hi
    __bf16* sAl = sAh + 64 * SA_STRIDE;        // lo
    __bf16* sBh = sAl + 64 * SA_STRIDE;        // Wc tile   [64 n][32 e] hi
    __bf16* sBl = sBh + 64 * SA_STRIDE;        // lo

    const int lane = tid & 63;
    const int w = __builtin_amdgcn_readfirstlane(tid >> 6);
    const int b  = bx >> 5;
    const int t  = bx & 31;
    const int p0 = (t >> 2) * 64;
    const int n0 = (t & 3) * 64;
    const bool do_bias = (n0 == 0);
    const int wm = (w >> 1) * 32, wn = (w & 1) * 32;
    const int ln = lane & 15, kq = (lane >> 4) * 8;
    const int ar = tid >> 2, ac = (tid & 3) * 8;

    f32x4 acc[2][2];
#pragma unroll
    for (int i = 0; i < 2; ++i)
#pragma unroll
        for (int j = 0; j < 2; ++j) acc[i][j] = (f32x4){0.f, 0.f, 0.f, 0.f};
    float bacc = 0.f;

    for (int k0 = 0; k0 < EE; k0 += 32) {
        {
            const float* ap = enc + ((size_t)(b * PP + p0 + ar)) * EE + k0 + ac;
            float4 f0 = *(const float4*)ap;
            float4 f1 = *(const float4*)(ap + 4);
            float v[8] = {f0.x, f0.y, f0.z, f0.w, f1.x, f1.y, f1.z, f1.w};
            bf16x8 h8, l8;
#pragma unroll
            for (int j = 0; j < 8; ++j) {
                __bf16 hh = (__bf16)v[j];
                h8[j] = hh;
                l8[j] = (__bf16)(v[j] - (float)hh);
            }
            if (do_bias) {
#pragma unroll
                for (int j = 0; j < 8; ++j) bacc += v[j] * bias[k0 + ac + j];
            }
            *(bf16x8*)&sAh[ar * SA_STRIDE + ac] = h8;
            *(bf16x8*)&sAl[ar * SA_STRIDE + ac] = l8;
        }
        {
            bf16x8 h8, l8;
            cvt_split8(Wc + (size_t)(n0 + ar) * EE + k0 + ac, h8, l8);
            *(bf16x8*)&sBh[ar * SA_STRIDE + ac] = h8;
            *(bf16x8*)&sBl[ar * SA_STRIDE + ac] = l8;
        }
        __syncthreads();

        bf16x8 ah[2], al[2];
#pragma unroll
        for (int mt = 0; mt < 2; ++mt) {
            ah[mt] = *(const bf16x8*)&sAh[(wm + mt * 16 + ln) * SA_STRIDE + kq];
            al[mt] = *(const bf16x8*)&sAl[(wm + mt * 16 + ln) * SA_STRIDE + kq];
        }
#pragma unroll
        for (int nt = 0; nt < 2; ++nt) {
            const int rowb = wn + nt * 16 + ln;
            bf16x8 bh8 = *(const bf16x8*)&sBh[rowb * SA_STRIDE + kq];
            bf16x8 bl8 = *(const bf16x8*)&sBl[rowb * SA_STRIDE + kq];
#pragma unroll
            for (int mt = 0; mt < 2; ++mt) {
                acc[mt][nt] = __builtin_amdgcn_mfma_f32_16x16x32_bf16(ah[mt], bh8, acc[mt][nt], 0, 0, 0);
                acc[mt][nt] = __builtin_amdgcn_mfma_f32_16x16x32_bf16(al[mt], bh8, acc[mt][nt], 0, 0, 0);
                acc[mt][nt] = __builtin_amdgcn_mfma_f32_16x16x32_bf16(ah[mt], bl8, acc[mt][nt], 0, 0, 0);
            }
        }
        __syncthreads();
    }

    if (do_bias) {
        bacc += __shfl_xor(bacc, 1);
        bacc += __shfl_xor(bacc, 2);
        if ((tid & 3) == 0) biasEnc[b * PP + p0 + ar] = bacc;
    }

    const int rbase = (lane >> 4) * 4;
#pragma unroll
    for (int mt = 0; mt < 2; ++mt)
#pragma unroll
        for (int nt = 0; nt < 2; ++nt)
#pragma unroll
            for (int r = 0; r < 4; ++r) {
                const int p = p0 + wm + mt * 16 + rbase + r;
                const int n = n0 + wn + nt * 16 + ln;
                const float v = acc[mt][nt][r];
                const __bf16 h = (__bf16)v;
                const size_t o = ((size_t)(b * PP + p)) * HK + n;
                W2th[o] = h;
                W2tl[o] = (__bf16)(v - (float)h);
            }
}

// ---------------------------------------------------------------------------
// weight_prep (round-9 arrangement): blocks [0,512) = W2 precompute;
// blocks [512,1344) = q1 partials + Wk/Wv/Wq transposes. Grid EXACTLY 1344.
// ---------------------------------------------------------------------------
__global__ __launch_bounds__(256) void weight_prep(const float* __restrict__ Wk,
                                                   const float* __restrict__ Wv,
                                                   const float* __restrict__ Wq,
                                                   const float* __restrict__ Wc,
                                                   const float* __restrict__ in1,
                                                   const float* __restrict__ enc,
                                                   const float* __restrict__ Wcb,
                                                   __bf16* __restrict__ wkt_h, __bf16* __restrict__ wkt_l,
                                                   __bf16* __restrict__ wvt_h, __bf16* __restrict__ wvt_l,
                                                   __bf16* __restrict__ wqt_h, __bf16* __restrict__ wqt_l,
                                                   float* __restrict__ q1p,
                                                   __bf16* __restrict__ W2th, __bf16* __restrict__ W2tl,
                                                   float* __restrict__ biasEnc)
{
    __shared__ __align__(16) unsigned char smem[4 * 64 * SA_STRIDE * 2];
    if (blockIdx.x < 512) {
        w2proj_body(blockIdx.x, threadIdx.x, smem, enc, Wc, Wcb, W2th, W2tl, biasEnc);
        return;
    }
    int gid = (blockIdx.x - 512) * 256 + threadIdx.x;
    if (gid < 16384) {
        const int b = gid >> 10, q = (gid >> 8) & 3, n = gid & 255;
        const float* ip = in1 + (size_t)b * EE + q * 64;
        const float* wp = Wq + (size_t)(q * 64) * HK + n;
        float acc = 0.f;
#pragma unroll 8
        for (int k = 0; k < 64; ++k) acc += ip[k] * wp[(size_t)k * HK];
        q1p[gid] = acc;
        return;
    }
    int id = gid - 16384;
    if (id >= 196608) return;   // guard: grid oversubscription must not write OOB
    const float* W;
    __bf16 *th, *tl;
    int krow = 0;
    if (id < 65536)       { W = Wk; th = wkt_h; tl = wkt_l; }
    else if (id < 131072) { id -= 65536;  W = Wv; th = wvt_h; tl = wvt_l; }
    else                  { id -= 131072; W = Wq; th = wqt_h; tl = wqt_l; krow = 256; }
    const int k = id & 255;
    const int n = id >> 8;
    const float v = W[(size_t)(k + krow) * HK + n];
    const __bf16 h = (__bf16)v;
    th[(n << 8) + k] = h;
    tl[(n << 8) + k] = (__bf16)(v - (float)h);
}

// ---------------------------------------------------------------------------
// K-only projection body (round 14: kvproj split into kproj+vproj so each
// body has ONE acc set (16 VGPRs) and 2-matrix B-staging -> kernel-wide VGPR
// drops enough for 3 blocks/CU without the round-1 spills).
// ---------------------------------------------------------------------------
__device__ inline void kproj_body(int bx, int tid, unsigned char* smem,
                                  const float* __restrict__ A,
                                  const __bf16* __restrict__ Bh,
                                  const __bf16* __restrict__ Bl,
                                  __bf16* __restrict__ Khi,
                                  __bf16* __restrict__ Klo)
{
    __bf16* sAh = (__bf16*)smem;               // [64][SA_STRIDE]
    __bf16* sAl = sAh + 64 * SA_STRIDE;
    __bf16* sB  = sAl + 64 * SA_STRIDE;        // [2][64][SA_STRIDE]

    const int lane = tid & 63;
    const int w = __builtin_amdgcn_readfirstlane(tid >> 6);
    const int m0 = (bx >> 2) * 64;
    const int n0 = (bx & 3) * 64;
    const int wm = (w >> 1) * 32, wn = (w & 1) * 32;
    const int ln = lane & 15, kq = (lane >> 4) * 8;
    const int ar = tid >> 2, ac = (tid & 3) * 8;

    f32x4 acc[2][2];
#pragma unroll
    for (int i = 0; i < 2; ++i)
#pragma unroll
        for (int j = 0; j < 2; ++j) acc[i][j] = (f32x4){0.f, 0.f, 0.f, 0.f};

    for (int k0 = 0; k0 < EE; k0 += 32) {
        {
            bf16x8 h8, l8;
            cvt_split8(A + (size_t)(m0 + ar) * EE + k0 + ac, h8, l8);
            *(bf16x8*)&sAh[ar * SA_STRIDE + ac] = h8;
            *(bf16x8*)&sAl[ar * SA_STRIDE + ac] = l8;
        }
        {
            const int mat = w >> 1;
            const int row = (w & 1) * 32 + (lane >> 1);
            const int halfk = (lane & 1) * 16;
            const __bf16* src = (mat ? Bl : Bh) + ((size_t)(n0 + row) << 8) + k0 + halfk;
            __bf16* dst = sB + (mat * 64 + row) * SA_STRIDE + halfk;
            *(bf16x8*)&dst[0] = *(const bf16x8*)&src[0];
            *(bf16x8*)&dst[8] = *(const bf16x8*)&src[8];
        }
        __syncthreads();

        bf16x8 ah[2], al[2];
#pragma unroll
        for (int mt = 0; mt < 2; ++mt) {
            ah[mt] = *(const bf16x8*)&sAh[(wm + mt * 16 + ln) * SA_STRIDE + kq];
            al[mt] = *(const bf16x8*)&sAl[(wm + mt * 16 + ln) * SA_STRIDE + kq];
        }
#pragma unroll
        for (int nt = 0; nt < 2; ++nt) {
            const int rowb = wn + nt * 16 + ln;
            bf16x8 bh8 = *(const bf16x8*)&sB[(0 * 64 + rowb) * SA_STRIDE + kq];
            bf16x8 bl8 = *(const bf16x8*)&sB[(1 * 64 + rowb) * SA_STRIDE + kq];
#pragma unroll
            for (int mt = 0; mt < 2; ++mt) {
                acc[mt][nt] = __builtin_amdgcn_mfma_f32_16x16x32_bf16(ah[mt], bh8, acc[mt][nt], 0, 0, 0);
                acc[mt][nt] = __builtin_amdgcn_mfma_f32_16x16x32_bf16(al[mt], bh8, acc[mt][nt], 0, 0, 0);
                acc[mt][nt] = __builtin_amdgcn_mfma_f32_16x16x32_bf16(ah[mt], bl8, acc[mt][nt], 0, 0, 0);
            }
        }
        __syncthreads();
    }

    __bf16* eKh = (__bf16*)smem;
    __bf16* eKl = eKh + 5120;

    const int rbase = (lane >> 4) * 4;
#pragma unroll
    for (int mt = 0; mt < 2; ++mt)
#pragma unroll
        for (int nt = 0; nt < 2; ++nt) {
            const int hloc = (w & 1) * 2 + nt;
#pragma unroll
            for (int r = 0; r < 4; ++r) {
                const int m = wm + mt * 16 + rbase + r;
                const float vk = acc[mt][nt][r];
                const __bf16 hk = (__bf16)vk;
                eKh[(hloc * 64 + m) * 20 + ln] = hk;
                eKl[(hloc * 64 + m) * 20 + ln] = (__bf16)(vk - (float)hk);
            }
        }
    __syncthreads();

    const int b = m0 >> 9;
    const int pbase = m0 & (PP - 1);
    {
        const int hl = tid >> 6, p = tid & 63;
        const int hg = (n0 >> 4) + hl;
        const size_t dst = (((size_t)b * HH + hg) * PP + pbase + p) * KD;
        const int base = (hl * 64 + p) * 20;
        uint2 a0 = *(const uint2*)&eKh[base + 0];
        uint2 a1 = *(const uint2*)&eKh[base + 4];
        uint2 a2 = *(const uint2*)&eKh[base + 8];
        uint2 a3 = *(const uint2*)&eKh[base + 12];
        *(uint4*)(Khi + dst)     = make_uint4(a0.x, a0.y, a1.x, a1.y);
        *(uint4*)(Khi + dst + 8) = make_uint4(a2.x, a2.y, a3.x, a3.y);
        uint2 c0 = *(const uint2*)&eKl[base + 0];
        uint2 c1 = *(const uint2*)&eKl[base + 4];
        uint2 c2 = *(const uint2*)&eKl[base + 8];
        uint2 c3 = *(const uint2*)&eKl[base + 12];
        *(uint4*)(Klo + dst)     = make_uint4(c0.x, c0.y, c1.x, c1.y);
        *(uint4*)(Klo + dst + 8) = make_uint4(c2.x, c2.y, c3.x, c3.y);
    }
}

// ---------------------------------------------------------------------------
// V-only projection body (same GEMM; epilogue transposes to Vt layout).
// ---------------------------------------------------------------------------
__device__ inline void vproj_body(int bx, int tid, unsigned char* smem,
                                  const float* __restrict__ A,
                                  const __bf16* __restrict__ Bh,
                                  const __bf16* __restrict__ Bl,
                                  __bf16* __restrict__ Vt)
{
    __bf16* sAh = (__bf16*)smem;               // [64][SA_STRIDE]
    __bf16* sAl = sAh + 64 * SA_STRIDE;
    __bf16* sB  = sAl + 64 * SA_STRIDE;        // [2][64][SA_STRIDE]

    const int lane = tid & 63;
    const int w = __builtin_amdgcn_readfirstlane(tid >> 6);
    const int m0 = (bx >> 2) * 64;
    const int n0 = (bx & 3) * 64;
    const int wm = (w >> 1) * 32, wn = (w & 1) * 32;
    const int ln = lane & 15, kq = (lane >> 4) * 8;
    const int ar = tid >> 2, ac = (tid & 3) * 8;

    f32x4 acc[2][2];
#pragma unroll
    for (int i = 0; i < 2; ++i)
#pragma unroll
        for (int j = 0; j < 2; ++j) acc[i][j] = (f32x4){0.f, 0.f, 0.f, 0.f};

    for (int k0 = 0; k0 < EE; k0 += 32) {
        {
            bf16x8 h8, l8;
            cvt_split8(A + (size_t)(m0 + ar) * EE + k0 + ac, h8, l8);
            *(bf16x8*)&sAh[ar * SA_STRIDE + ac] = h8;
            *(bf16x8*)&sAl[ar * SA_STRIDE + ac] = l8;
        }
        {
            const int mat = w >> 1;
            const int row = (w & 1) * 32 + (lane >> 1);
            const int halfk = (lane & 1) * 16;
            const __bf16* src = (mat ? Bl : Bh) + ((size_t)(n0 + row) << 8) + k0 + halfk;
            __bf16* dst = sB + (mat * 64 + row) * SA_STRIDE + halfk;
            *(bf16x8*)&dst[0] = *(const bf16x8*)&src[0];
            *(bf16x8*)&dst[8] = *(const bf16x8*)&src[8];
        }
        __syncthreads();

        bf16x8 ah[2], al[2];
#pragma unroll
        for (int mt = 0; mt < 2; ++mt) {
            ah[mt] = *(const bf16x8*)&sAh[(wm + mt * 16 + ln) * SA_STRIDE + kq];
            al[mt] = *(const bf16x8*)&sAl[(wm + mt * 16 + ln) * SA_STRIDE + kq];
        }
#pragma unroll
        for (int nt = 0; nt < 2; ++nt) {
            const int rowb = wn + nt * 16 + ln;
            bf16x8 bh8 = *(const bf16x8*)&sB[(0 * 64 + rowb) * SA_STRIDE + kq];
            bf16x8 bl8 = *(const bf16x8*)&sB[(1 * 64 + rowb) * SA_STRIDE + kq];
#pragma unroll
            for (int mt = 0; mt < 2; ++mt) {
                acc[mt][nt] = __builtin_amdgcn_mfma_f32_16x16x32_bf16(ah[mt], bh8, acc[mt][nt], 0, 0, 0);
                acc[mt][nt] = __builtin_amdgcn_mfma_f32_16x16x32_bf16(al[mt], bh8, acc[mt][nt], 0, 0, 0);
                acc[mt][nt] = __builtin_amdgcn_mfma_f32_16x16x32_bf16(ah[mt], bl8, acc[mt][nt], 0, 0, 0);
            }
        }
        __syncthreads();
    }

    __bf16* eV = (__bf16*)smem;   // [64 n][68]

    const int rbase = (lane >> 4) * 4;
#pragma unroll
    for (int mt = 0; mt < 2; ++mt)
#pragma unroll
        for (int nt = 0; nt < 2; ++nt) {
            const int nl = wn + nt * 16 + ln;
#pragma unroll
            for (int r = 0; r < 4; ++r) {
                const int m = wm + mt * 16 + rbase + r;
                eV[nl * 68 + m] = (__bf16)acc[mt][nt][r];
            }
        }
    __syncthreads();

    const int b = m0 >> 9;
    const int pbase = m0 & (PP - 1);
    {
        const int n = tid >> 2, qq = tid & 3;
        const int ng = n0 + n, hg = ng >> 4, kk = ng & 15;
        const int base = n * 68 + qq * 16;
        uint2 v0 = *(const uint2*)&eV[base + 0];
        uint2 v1 = *(const uint2*)&eV[base + 4];
        uint2 v2 = *(const uint2*)&eV[base + 8];
        uint2 v3 = *(const uint2*)&eV[base + 12];
        const size_t dst = ((((size_t)b * HH + hg) * KD + kk) * PP) + pbase + qq * 16;
        *(uint4*)(Vt + dst)     = make_uint4(v0.x, v0.y, v1.x, v1.y);
        *(uint4*)(Vt + dst + 8) = make_uint4(v2.x, v2.y, v3.x, v3.y);
    }
}

// ---------------------------------------------------------------------------
// LDS-staged Q projection body (verified; unchanged).
// ---------------------------------------------------------------------------
__device__ inline void qproj_body(int bx, int tid, unsigned char* smem,
                                  const float* __restrict__ in2,
                                  const float* __restrict__ ct,
                                  const __bf16* __restrict__ Bh,
                                  const __bf16* __restrict__ Bl,
                                  const float* __restrict__ WqFull,
                                  const float* __restrict__ q1p,
                                  __bf16* __restrict__ Qhi,
                                  __bf16* __restrict__ Qlo)
{
    __bf16* sAh = (__bf16*)smem;
    __bf16* sAl = sAh + 64 * SA_STRIDE;
    __bf16* sB  = sAl + 64 * SA_STRIDE;

    const int lane = tid & 63;
    const int w = __builtin_amdgcn_readfirstlane(tid >> 6);
    const int m0 = (bx >> 2) * 64;
    const int n0 = (bx & 3) * 64;
    const int wm = (w >> 1) * 32, wn = (w & 1) * 32;
    const int ln = lane & 15, kq = (lane >> 4) * 8;
    const int ar = tid >> 2, ac = (tid & 3) * 8;
    const int b = m0 >> 9;
    const float* WqLast = WqFull + (size_t)512 * HK;

    f32x4 acc[2][2];
#pragma unroll
    for (int i = 0; i < 2; ++i)
#pragma unroll
        for (int j = 0; j < 2; ++j) acc[i][j] = (f32x4){0.f, 0.f, 0.f, 0.f};

    for (int k0 = 0; k0 < EE; k0 += 32) {
        {
            bf16x8 h8, l8;
            cvt_split8(in2 + (size_t)(m0 + ar) * EE + k0 + ac, h8, l8);
            *(bf16x8*)&sAh[ar * SA_STRIDE + ac] = h8;
            *(bf16x8*)&sAl[ar * SA_STRIDE + ac] = l8;
        }
        {
            const int mat = w >> 1;
            const int row = (w & 1) * 32 + (lane >> 1);
            const int half = (lane & 1) * 16;
            const __bf16* src = (mat ? Bl : Bh) + ((size_t)(n0 + row) << 8) + k0 + half;
            __bf16* dst = sB + (mat * 64 + row) * SA_STRIDE + half;
            *(bf16x8*)&dst[0] = *(const bf16x8*)&src[0];
            *(bf16x8*)&dst[8] = *(const bf16x8*)&src[8];
        }
        __syncthreads();

        bf16x8 ah[2], al[2];
#pragma unroll
        for (int mt = 0; mt < 2; ++mt) {
            ah[mt] = *(const bf16x8*)&sAh[(wm + mt * 16 + ln) * SA_STRIDE + kq];
            al[mt] = *(const bf16x8*)&sAl[(wm + mt * 16 + ln) * SA_STRIDE + kq];
        }
#pragma unroll
        for (int nt = 0; nt < 2; ++nt) {
            const int rowb = wn + nt * 16 + ln;
            bf16x8 bh8 = *(const bf16x8*)&sB[(0 * 64 + rowb) * SA_STRIDE + kq];
            bf16x8 bl8 = *(const bf16x8*)&sB[(1 * 64 + rowb) * SA_STRIDE + kq];
#pragma unroll
            for (int mt = 0; mt < 2; ++mt) {
                acc[mt][nt] = __builtin_amdgcn_mfma_f32_16x16x32_bf16(ah[mt], bh8, acc[mt][nt], 0, 0, 0);
                acc[mt][nt] = __builtin_amdgcn_mfma_f32_16x16x32_bf16(al[mt], bh8, acc[mt][nt], 0, 0, 0);
                acc[mt][nt] = __builtin_amdgcn_mfma_f32_16x16x32_bf16(ah[mt], bl8, acc[mt][nt], 0, 0, 0);
            }
        }
        __syncthreads();
    }

    __bf16* eQh = (__bf16*)smem;
    __bf16* eQl = eQh + 5120;

    const int rbase = (lane >> 4) * 4;
#pragma unroll
    for (int mt = 0; mt < 2; ++mt)
#pragma unroll
        for (int nt = 0; nt < 2; ++nt) {
            const int hloc = (w & 1) * 2 + nt;
            const int ng = n0 + wn + nt * 16 + ln;
            const float wq = WqLast[ng];
            const float q1v = q1p[b * 1024 + 0 * 256 + ng] + q1p[b * 1024 + 1 * 256 + ng]
                            + q1p[b * 1024 + 2 * 256 + ng] + q1p[b * 1024 + 3 * 256 + ng];
#pragma unroll
            for (int r = 0; r < 4; ++r) {
                const int m = wm + mt * 16 + rbase + r;
                const float v = acc[mt][nt][r] + q1v + ct[m0 + m] * wq;
                const __bf16 h = (__bf16)v;
                eQh[(hloc * 64 + m) * 20 + ln] = h;
                eQl[(hloc * 64 + m) * 20 + ln] = (__bf16)(v - (float)h);
            }
        }
    __syncthreads();

    {
        const int hl = tid >> 6, p = tid & 63;
        const int hg = (n0 >> 4) + hl;
        const int g = (m0 & (GG - 1)) + p;
        const size_t dst = (((size_t)b * HH + hg) * GG + g) * KD;
        const int base = (hl * 64 + p) * 20;
        uint2 a0 = *(const uint2*)&eQh[base + 0];
        uint2 a1 = *(const uint2*)&eQh[base + 4];
        uint2 a2 = *(const uint2*)&eQh[base + 8];
        uint2 a3 = *(const uint2*)&eQh[base + 12];
        *(uint4*)(Qhi + dst)     = make_uint4(a0.x, a0.y, a1.x, a1.y);
        *(uint4*)(Qhi + dst + 8) = make_uint4(a2.x, a2.y, a3.x, a3.y);
        uint2 c0 = *(const uint2*)&eQl[base + 0];
        uint2 c1 = *(const uint2*)&eQl[base + 4];
        uint2 c2 = *(const uint2*)&eQl[base + 8];
        uint2 c3 = *(const uint2*)&eQl[base + 12];
        *(uint4*)(Qlo + dst)     = make_uint4(c0.x, c0.y, c1.x, c1.y);
        *(uint4*)(Qlo + dst + 8) = make_uint4(c2.x, c2.y, c3.x, c3.y);
    }
}

// ---------------------------------------------------------------------------
// Fused K + V + Q projections (round 14): 1536 blocks, each body light
// (single acc set) -> (256,3) for 3 blocks/CU (12 waves/CU vs prior 8).
// [0,512) kproj | [512,1024) vproj | [1024,1536) qproj.
// ---------------------------------------------------------------------------
__global__ __launch_bounds__(256, 3) void fused_proj(const float* __restrict__ enc,
                                                     const __bf16* __restrict__ Bkh,
                                                     const __bf16* __restrict__ Bkl,
                                                     const __bf16* __restrict__ Bvh,
                                                     const __bf16* __restrict__ Bvl,
                                                     __bf16* __restrict__ Khi,
                                                     __bf16* __restrict__ Klo,
                                                     __bf16* __restrict__ Vt,
                                                     const float* __restrict__ in2,
                                                     const float* __restrict__ ct,
                                                     const __bf16* __restrict__ Bqh,
                                                     const __bf16* __restrict__ Bql,
                                                     const float* __restrict__ WqFull,
                                                     const float* __restrict__ q1p,
                                                     __bf16* __restrict__ Qhi,
                                                     __bf16* __restrict__ Qlo)
{
    __shared__ __align__(16) unsigned char smem[SMEM_BYTES];
    const int id = blockIdx.x;
    if (id < 512)
        kproj_body(id, threadIdx.x, smem, enc, Bkh, Bkl, Khi, Klo);
    else if (id < 1024)
        vproj_body(id - 512, threadIdx.x, smem, enc, Bvh, Bvl, Vt);
    else
        qproj_body(id - 1024, threadIdx.x, smem, in2, ct, Bqh, Bql, WqFull, q1p, Qhi, Qlo);
}

// ---------------------------------------------------------------------------
// Fused attention + pointer head (round-13 swapped-QK body, unchanged).
// ---------------------------------------------------------------------------
#define AT_STRIDE 264    // 256 + 8 pad
#define MSK_STRIDE 516   // 512 + 4 pad (f32): float4-aligned, <=4-way banks

__global__ __launch_bounds__(1024, 4) void attn_ptr(const __bf16* __restrict__ Qhi,
                                                    const __bf16* __restrict__ Qlo,
                                                    const __bf16* __restrict__ Khi,
                                                    const __bf16* __restrict__ Klo,
                                                    const __bf16* __restrict__ Vt,
                                                    const __bf16* __restrict__ w2_hi,
                                                    const __bf16* __restrict__ w2_lo,
                                                    const float* __restrict__ biasEnc,
                                                    const float* __restrict__ mask,
                                                    float* __restrict__ out)
{
    __shared__ __align__(16) float smask[32][MSK_STRIDE]; // 66 KB, mask slice
    __shared__ float srs[16][32];                         // row-sums / swsum
    __shared__ __align__(16) __bf16 sAth[32][AT_STRIDE];  // 16.9 KB, At hi
    __shared__ __align__(16) __bf16 sAtl[32][AT_STRIDE];  // 16.9 KB, At lo

    const int t = threadIdx.x;
    const int lane = t & 63;
    const int w = __builtin_amdgcn_readfirstlane(t >> 6);  // 0..15
    const int id = blockIdx.x;
    const int b = id & 15;                 // XCD pin: id%8 == b%8
    const int g0 = (id >> 4) * 32;
    const int ln32 = lane & 31;
    const int half = lane >> 5;
    const int h = w;                       // wave = head

    // ---- cooperative mask staging: 16384 f32 = 4 float4 per thread --------
    {
        const float* msrc = mask + ((size_t)(b * GG + g0)) * PP;
#pragma unroll
        for (int i = 0; i < 4; ++i) {
            const int c = (t + i * 1024) * 4;
            const int row = c >> 9, col = c & 511;
            *(float4*)&smask[row][col] = *(const float4*)&msrc[row * 512 + col];
        }
    }
    __syncthreads();   // mask staging visible to all waves

    // ================= attn phase (swapped QK) ==============================
    const size_t qbase = (((size_t)b * HH + h) * GG + g0) * KD;
    const size_t kbase = ((size_t)b * HH + h) * PP * KD;
    const size_t vbase = ((size_t)b * HH + h) * KD * PP;

    bf16x8 qah = *(const bf16x8*)(Qhi + qbase + (size_t)ln32 * KD + half * 8);
    bf16x8 qal = *(const bf16x8*)(Qlo + qbase + (size_t)ln32 * KD + half * 8);

    float rs = 0.f;
    f32x16 acc = (f32x16){0.f, 0.f, 0.f, 0.f, 0.f, 0.f, 0.f, 0.f,
                          0.f, 0.f, 0.f, 0.f, 0.f, 0.f, 0.f, 0.f};
    const int dv = ln32 & 15;   // V row (d), duplicated for ln32>=16

#pragma unroll 4
    for (int pc = 0; pc < 16; ++pc) {
        const int pb = pc * 32;
        const size_t ko = kbase + (size_t)(pb + ln32) * KD + half * 8;
        bf16x8 kh = *(const bf16x8*)(Khi + ko);
        bf16x8 kl = *(const bf16x8*)(Klo + ko);
        bf16x8 vb0 = *(const bf16x8*)(Vt + vbase + (size_t)dv * PP + pb + half * 8);
        bf16x8 vb1 = *(const bf16x8*)(Vt + vbase + (size_t)dv * PP + pb + 16 + half * 8);

        f32x16 s = (f32x16){0.f, 0.f, 0.f, 0.f, 0.f, 0.f, 0.f, 0.f,
                            0.f, 0.f, 0.f, 0.f, 0.f, 0.f, 0.f, 0.f};
        __builtin_amdgcn_s_setprio(1);
        s = __builtin_amdgcn_mfma_f32_32x32x16_bf16(kh, qah, s, 0, 0, 0);   // S^T
        s = __builtin_amdgcn_mfma_f32_32x32x16_bf16(kh, qal, s, 0, 0, 0);
        s = __builtin_amdgcn_mfma_f32_32x32x16_bf16(kl, qah, s, 0, 0, 0);
        __builtin_amdgcn_s_setprio(0);

        // mask: g = ln32 row, p = pb + prow(r,half); 4 float4 reads
        const float4 m0 = *(const float4*)&smask[ln32][pb + 0  + 4 * half];
        const float4 m1 = *(const float4*)&smask[ln32][pb + 8  + 4 * half];
        const float4 m2 = *(const float4*)&smask[ln32][pb + 16 + 4 * half];
        const float4 m3 = *(const float4*)&smask[ln32][pb + 24 + 4 * half];
        s[0]  = __expf(s[0]  * 0.25f + m0.x);
        s[1]  = __expf(s[1]  * 0.25f + m0.y);
        s[2]  = __expf(s[2]  * 0.25f + m0.z);
        s[3]  = __expf(s[3]  * 0.25f + m0.w);
        s[4]  = __expf(s[4]  * 0.25f + m1.x);
        s[5]  = __expf(s[5]  * 0.25f + m1.y);
        s[6]  = __expf(s[6]  * 0.25f + m1.z);
        s[7]  = __expf(s[7]  * 0.25f + m1.w);
        s[8]  = __expf(s[8]  * 0.25f + m2.x);
        s[9]  = __expf(s[9]  * 0.25f + m2.y);
        s[10] = __expf(s[10] * 0.25f + m2.z);
        s[11] = __expf(s[11] * 0.25f + m2.w);
        s[12] = __expf(s[12] * 0.25f + m3.x);
        s[13] = __expf(s[13] * 0.25f + m3.y);
        s[14] = __expf(s[14] * 0.25f + m3.z);
        s[15] = __expf(s[15] * 0.25f + m3.w);
#pragma unroll
        for (int r = 0; r < 16; ++r) rs += s[r];

        // pack P (bf16) and redistribute halves
        const int w01 = cvt_pk_bf16(s[0],  s[1]);
        const int w23 = cvt_pk_bf16(s[2],  s[3]);
        const int w45 = cvt_pk_bf16(s[4],  s[5]);
        const int w67 = cvt_pk_bf16(s[6],  s[7]);
        const int w89 = cvt_pk_bf16(s[8],  s[9]);
        const int wAB = cvt_pk_bf16(s[10], s[11]);
        const int wCD = cvt_pk_bf16(s[12], s[13]);
        const int wEF = cvt_pk_bf16(s[14], s[15]);
        const int x1 = half ? w01 : w45;
        const int x2 = half ? w23 : w67;
        const int x3 = half ? w89 : wCD;
        const int x4 = half ? wAB : wEF;
        const int p1 = __shfl_xor(x1, 32);
        const int p2 = __shfl_xor(x2, 32);
        const int p3 = __shfl_xor(x3, 32);
        const int p4 = __shfl_xor(x4, 32);
        i32x4 f0 = half ? (i32x4){p1, p2, w45, w67} : (i32x4){w01, w23, p1, p2};
        i32x4 f1 = half ? (i32x4){p3, p4, wCD, wEF} : (i32x4){w89, wAB, p3, p4};
        bf16x8 pa0 = *(bf16x8*)&f0;
        bf16x8 pa1 = *(bf16x8*)&f1;

        __builtin_amdgcn_s_setprio(1);
        acc = __builtin_amdgcn_mfma_f32_32x32x16_bf16(pa0, vb0, acc, 0, 0, 0);
        acc = __builtin_amdgcn_mfma_f32_32x32x16_bf16(pa1, vb1, acc, 0, 0, 0);
        __builtin_amdgcn_s_setprio(0);
    }

    // total row-sum for g = ln32: own half + partner half
    rs += __shfl_xor(rs, 32);
    if (half == 0) srs[w][ln32] = rs;

    // O layout: col = d = ln32 (valid < 16), reg r -> g = prow(r,half).
    if (ln32 < 16) {
#pragma unroll
        for (int r = 0; r < 16; ++r) {
            const int g = (r & 3) + 8 * (r >> 2) + 4 * half;
            const float v = acc[r] / srs[w][g];
            const __bf16 hv = (__bf16)v;
            sAth[g][w * 16 + ln32] = hv;
            sAtl[g][w * 16 + ln32] = (__bf16)(v - (float)hv);
        }
    }
    __syncthreads();

    // ================= pointer phase (A from LDS) ===========================
    const size_t brow = ((size_t)(b * PP + w * 32 + ln32)) * HK + half * 8;
    const float be = biasEnc[b * PP + w * 32 + ln32];

    f32x16 acc0 = (f32x16){0.f, 0.f, 0.f, 0.f, 0.f, 0.f, 0.f, 0.f,
                           0.f, 0.f, 0.f, 0.f, 0.f, 0.f, 0.f, 0.f};
    f32x16 acc1 = acc0, acc2 = acc0;

#pragma unroll 4
    for (int kc = 0; kc < HK; kc += 16) {
        bf16x8 ah = *(const bf16x8*)&sAth[ln32][kc + half * 8];
        bf16x8 al = *(const bf16x8*)&sAtl[ln32][kc + half * 8];
        bf16x8 bh = *(const bf16x8*)(w2_hi + brow + kc);
        bf16x8 bl = *(const bf16x8*)(w2_lo + brow + kc);
        __builtin_amdgcn_s_setprio(1);
        acc0 = __builtin_amdgcn_mfma_f32_32x32x16_bf16(ah, bh, acc0, 0, 0, 0);
        acc1 = __builtin_amdgcn_mfma_f32_32x32x16_bf16(al, bh, acc1, 0, 0, 0);
        acc2 = __builtin_amdgcn_mfma_f32_32x32x16_bf16(ah, bl, acc2, 0, 0, 0);
        __builtin_amdgcn_s_setprio(0);
    }

    f32x16 pacc = acc0 + acc1 + acc2;

    float rsum[16];
#pragma unroll
    for (int r = 0; r < 16; ++r) {
        const int row = (r & 3) + 8 * (r >> 2) + 4 * half;
        float sc = (pacc[r] + be) * 0.0625f;             // 1/sqrt(256)
        sc = fminf(9.f, fmaxf(-9.f, sc));
        const float e2 = __expf(2.f * sc);
        const float th = (e2 - 1.f) / (e2 + 1.f);        // tanh(sc)
        const float m = smask[row][w * 32 + ln32];
        const float e = __expf(10.f * th + m);           // bounded by e^10
        pacc[r] = e;
        rsum[r] = e;
    }

#pragma unroll
    for (int r = 0; r < 16; ++r) {
        rsum[r] += __shfl_xor(rsum[r], 1);
        rsum[r] += __shfl_xor(rsum[r], 2);
        rsum[r] += __shfl_xor(rsum[r], 4);
        rsum[r] += __shfl_xor(rsum[r], 8);
        rsum[r] += __shfl_xor(rsum[r], 16);
    }
    if (ln32 == 0) {
#pragma unroll
        for (int r = 0; r < 16; ++r)
            srs[w][(r & 3) + 8 * (r >> 2) + 4 * half] = rsum[r];   // reuse as swsum
    }
    __syncthreads();

    float inv[16];
#pragma unroll
    for (int r = 0; r < 16; ++r) {
        const int row = (r & 3) + 8 * (r >> 2) + 4 * half;
        float tot = 0.f;
#pragma unroll
        for (int wv = 0; wv < 16; ++wv) tot += srs[wv][row];  // LDS broadcast
        inv[r] = 1.f / tot;
    }

#pragma unroll
    for (int r = 0; r < 16; ++r) {
        const int row = (r & 3) + 8 * (r >> 2) + 4 * half;
        out[((size_t)(b * GG + g0 + row)) * PP + w * 32 + ln32] = pacc[r] * inv[r];
    }
}

// ---------------------------------------------------------------------------
extern "C" void kernel_launch(void* const* d_in, const int* in_sizes, int n_in,
                              void* d_out, int out_size, void* d_ws, size_t ws_size,
                              hipStream_t stream)
{
    const float* in1  = (const float*)d_in[0];
    const float* in2  = (const float*)d_in[1];
    const float* ct   = (const float*)d_in[2];
    const float* mask = (const float*)d_in[3];
    const float* enc  = (const float*)d_in[4];
    const float* Wq   = (const float*)d_in[5];
    const float* Wk   = (const float*)d_in[6];
    const float* Wv   = (const float*)d_in[7];
    const float* Wcw  = (const float*)d_in[8];
    const float* Wcb  = (const float*)d_in[9];
    float* out = (float*)d_out;
    float* ws  = (float*)d_ws;

    const size_t SEG = (size_t)BB * GG * HK;  // 2M elements
    __bf16* Khi = (__bf16*)ws;
    __bf16* Klo = Khi + SEG;
    __bf16* Vt  = (__bf16*)(ws + SEG);
    __bf16* Qhi = (__bf16*)(ws + 2 * SEG);
    __bf16* Qlo = Qhi + SEG;
    __bf16* wkt_h = (__bf16*)(ws + 3 * SEG);   // 6 x 65536 bf16 = 196608 floats
    __bf16* wkt_l = wkt_h + 65536;
    __bf16* wvt_h = wkt_l + 65536;
    __bf16* wvt_l = wvt_h + 65536;
    __bf16* wqt_h = wvt_l + 65536;             // Wq rows 256..511 only
    __bf16* wqt_l = wqt_h + 65536;
    float*  q1p     = ws + 3 * SEG + 196608;   // [B][4][HK] fp32 partials
    float*  biasEnc = q1p + 16384;             // [B][P] fp32
    __bf16* W2th  = (__bf16*)(ws + 4 * SEG);   // [B][P][HK] hi
    __bf16* W2tl  = W2th + SEG;                // lo

    const dim3 blk(256);

    weight_prep<<<dim3(1344), blk, 0, stream>>>(Wk, Wv, Wq, Wcw, in1, enc, Wcb,
                                                wkt_h, wkt_l, wvt_h, wvt_l,
                                                wqt_h, wqt_l, q1p,
                                                W2th, W2tl, biasEnc);

    fused_proj<<<dim3(1536), blk, 0, stream>>>(enc, wkt_h, wkt_l, wvt_h, wvt_l,
                                               Khi, Klo, Vt,
                                               in2, ct, wqt_h, wqt_l, Wq, q1p,
                                               Qhi, Qlo);

    attn_ptr<<<dim3(256), dim3(1024), 0, stream>>>(Qhi, Qlo, Khi, Klo, Vt,
                                                   W2th, W2tl, biasEnc, mask, out);
}